// Round 21
// baseline (1740.741 us; speedup 1.0000x reference)
//
#include <hip/hip_runtime.h>
#include <hip/hip_bf16.h>

typedef __bf16 bf16;
typedef __bf16 bf16x8 __attribute__((ext_vector_type(8)));
typedef float f32x4 __attribute__((ext_vector_type(4)));
typedef unsigned int u32x4 __attribute__((ext_vector_type(4)));

#define B_SZ 32
#define T_SZ 64
#define H_SZ 512
#define V_SZ 32000
#define NWG_REC 8
#define NTILES 250
#define MTILES 16

__device__ __forceinline__ float sigmoidf_(float v) { return 1.0f / (1.0f + expf(-v)); }

__device__ __forceinline__ bf16x8 cvt8(const float* __restrict__ p) {
  float4 a = *(const float4*)p;
  float4 b = *(const float4*)(p + 4);
  bf16x8 o;
  o[0] = (bf16)a.x; o[1] = (bf16)a.y; o[2] = (bf16)a.z; o[3] = (bf16)a.w;
  o[4] = (bf16)b.x; o[5] = (bf16)b.y; o[6] = (bf16)b.z; o[7] = (bf16)b.w;
  return o;
}

// ---- LLC-coherent primitives (bypass L1/L2 via sc0 sc1) ----
#define GLD(dst, base, off) \
  asm volatile("global_load_dwordx4 %0, %1, off offset:" off " sc0 sc1" \
               : "=v"(dst) : "v"(base))
#define GST2(base, off, val) do { \
  unsigned int w_ = (unsigned int)__builtin_bit_cast(unsigned short, (bf16)(val)); \
  asm volatile("global_store_short %0, %1, off offset:" off " sc0 sc1" \
               :: "v"(base), "v"(w_) : "memory"); \
} while (0)
#define WAITV  asm volatile("s_waitcnt vmcnt(0)" ::: "memory")
#define SCHEDB __builtin_amdgcn_sched_barrier(0)

__device__ __forceinline__ int llc_poll(const int* p) {
  int r;
  asm volatile("global_load_dword %0, %1, off sc0 sc1\n\ts_waitcnt vmcnt(0)"
               : "=v"(r) : "v"(p) : "memory");
  return r;
}

// ---------------- merged prologue: x-proj GEMM + fc_w cvt + prep ----------------
__global__ __launch_bounds__(256) void xproj_k(
    const int* __restrict__ caps, const float* __restrict__ emb,
    const float* __restrict__ B0, const float* __restrict__ B1, const float* __restrict__ B2,
    const float* __restrict__ bias0, const float* __restrict__ bias1, const float* __restrict__ bias2,
    float* __restrict__ C, int gemm_blocks, int prep_start,
    const float* __restrict__ fcw_src, bf16* __restrict__ fcw_dst,
    const float* __restrict__ feat, bf16* __restrict__ hs, int* __restrict__ ctr,
    bf16* __restrict__ whp_dst)
{
  __shared__ __align__(16) bf16 lA[128 * 32];
  __shared__ __align__(16) bf16 lB[128 * 32];
  const int tid = threadIdx.x;
  const int bidx = blockIdx.x;

  if (bidx >= prep_start) {               // prep: Wh-part extract + h0 + flags
    int i = (bidx - prep_start) * 256 + tid;   // 98304 threads
    int w = i >> 15;
    int rem = i & 32767;
    int n = rem >> 6;
    int k8 = (rem & 63) * 8;
    const float* W = (w == 0) ? B0 : (w == 1) ? B1 : B2;
    *(bf16x8*)(whp_dst + (long)w * 262144 + n * 512 + k8) = cvt8(W + (long)n * 1024 + 512 + k8);
    if (i < B_SZ * H_SZ) hs[i] = (bf16)feat[i];   // h0 -> hs slab 0
    if (i < 128) ctr[i] = 0;
    return;
  }

  if (bidx >= gemm_blocks) {              // fc_w f32->bf16 cvt
    long base = ((long)(bidx - gemm_blocks) * 256 + tid) * 8;
    const long stride = (long)128 * 256 * 8;
    for (long i = base; i < (long)V_SZ * H_SZ; i += stride)
      *(bf16x8*)(fcw_dst + i) = cvt8(fcw_src + i);
    return;
  }

  const int lane = tid & 63;
  const int l15  = lane & 15;
  const int kb8  = (lane >> 4) * 8;
  const int wid  = tid >> 6;
  const int wm   = wid >> 1, wn = wid & 1;
  const int mtile = bidx % 16, ntile = bidx / 16;
  const int m0 = mtile * 128, n0 = ntile * 128;

  int wsel = n0 >> 9;
  const float* Bv   = wsel == 0 ? B0 : wsel == 1 ? B1 : B2;
  const float* bias = wsel == 0 ? bias0 : wsel == 1 ? bias1 : bias2;
  int nb = n0 & 511;

  f32x4 acc[4][4] = {};

  for (int k0 = 0; k0 < 512; k0 += 32) {
    #pragma unroll
    for (int j = 0; j < 2; ++j) {
      int c = j * 256 + tid;
      int row = c >> 2;
      int kc = (c & 3) * 8;
      *(bf16x8*)&lA[row * 32 + kc] = cvt8(emb + (long)caps[m0 + row] * 512 + k0 + kc);
      *(bf16x8*)&lB[row * 32 + kc] = cvt8(Bv + (long)(nb + row) * 1024 + k0 + kc);
    }
    __syncthreads();
    bf16x8 af[4], bfr[4];
    #pragma unroll
    for (int mf = 0; mf < 4; ++mf)
      af[mf] = *(const bf16x8*)&lA[(wm * 64 + mf * 16 + l15) * 32 + kb8];
    #pragma unroll
    for (int nf = 0; nf < 4; ++nf)
      bfr[nf] = *(const bf16x8*)&lB[(wn * 64 + nf * 16 + l15) * 32 + kb8];
    #pragma unroll
    for (int mf = 0; mf < 4; ++mf)
      #pragma unroll
      for (int nf = 0; nf < 4; ++nf)
        acc[mf][nf] = __builtin_amdgcn_mfma_f32_16x16x32_bf16(af[mf], bfr[nf], acc[mf][nf], 0, 0, 0);
    __syncthreads();
  }

  #pragma unroll
  for (int mf = 0; mf < 4; ++mf)
    #pragma unroll
    for (int nf = 0; nf < 4; ++nf)
      #pragma unroll
      for (int r = 0; r < 4; ++r) {
        int row = m0 + wm * 64 + mf * 16 + (lane >> 4) * 4 + r;
        int lc  = wn * 64 + nf * 16 + l15;
        C[(long)row * 1536 + n0 + lc] = acc[mf][nf][r] + bias[nb + lc];
      }
}

// ---------------- FUSED: 1-barrier/step recurrence + gated logits workers -------------
// Rec wg bid owns output cols bid*128..+127 (waves: 16 cols each) for its group's 16
// batch rows (grp=bid>>2). Per step:
//   stage h(t) [16x512] from hs slab t -> LDS;
//   z (own 16 cols, pinned Bz) + r for ALL 512 cols (wave wid: cols wid*64..+63, Wr
//   streamed from L2) -> r*h into LDS rh tile (wg-local!);
//   __syncthreads; h_tilde (own cols, pinned Bh) + blend; h(t+1) -> hs slab t+1;
//   ONE grid barrier (per-group ctr, 4 arrivals).
// ctr[0]/ctr[32]: group RMW lines. ctr[64]/ctr[96]: read-only prog lines.
__global__ __launch_bounds__(512, 2) void fused_k(
    const float* __restrict__ X,
    const bf16* __restrict__ Wzh, const bf16* __restrict__ Wrh, const bf16* __restrict__ Whh,
    const float* __restrict__ feat,
    bf16* __restrict__ hs, int* __restrict__ ctr,
    const bf16* __restrict__ fcw16, const float* __restrict__ fcw_f32,
    const float* __restrict__ fc_b, float* __restrict__ out, int use_bf16B)
{
  __shared__ __align__(16) char smem[32768];
  const int tid  = threadIdx.x;                   // 0..511
  const int bid  = blockIdx.x;
  const int lane = tid & 63;
  const int l15  = lane & 15;
  const int q    = lane >> 4;                     // 0..3

  if (bid < NWG_REC) {
    // ================= 1-barrier recurrence =================
    char* h_lds  = smem;                          // 16x512 bf16, swizzled, 16KB
    char* rh_lds = smem + 16384;                  // 16x512 bf16, swizzled, 16KB
    const int wid  = tid >> 6;                    // wave 0..7
    const int kb   = q * 8;
    const int grp  = bid >> 2;
    const int b0   = grp * 16;
    const int ocol = (bid & 3) * 128 + wid * 16 + l15;   // own z/h column
    int* mctr  = ctr + grp * 32;
    int* progG = ctr + 64 + grp * 32;

    // own-column weights (pin attempt; partial spill streams from L2 — proven ok)
    u32x4 Bz[16], Bh[16];
    #pragma unroll
    for (int kk = 0; kk < 16; ++kk) {
      Bz[kk] = *(const u32x4*)(Wzh + (long)ocol * 512 + kk * 32 + kb);
      Bh[kk] = *(const u32x4*)(Whh + (long)ocol * 512 + kk * 32 + kb);
    }
    #pragma unroll
    for (int kk = 0; kk < 16; ++kk)
      asm volatile("" : "+v"(Bz[kk]), "+v"(Bh[kk]));

    float hprev[4];
    #pragma unroll
    for (int r = 0; r < 4; ++r) hprev[r] = feat[(b0 + q * 4 + r) * 512 + ocol];

    // staging offsets (16 rows x 1024B, XOR swizzle)
    const int srow0 = tid >> 6;
    const int soff0 = (tid * 16) ^ ((srow0 & 7) << 4);
    const int soff1 = (8192 + tid * 16) ^ ((srow0 & 7) << 4);
    const int fbase = (l15 * 1024 + q * 16) ^ ((l15 & 7) << 4);

    int epoch = 0;
    for (int t = 0; t < T_SZ; ++t) {
      // ---- stage h(t) from hs slab t -> LDS ----
      {
        const bf16* src = hs + (long)(t * 32 + b0) * 512;
        u32x4 v0, v1;
        GLD(v0, src + tid * 8, "0");
        GLD(v1, src + 4096 + tid * 8, "0");
        WAITV;
        SCHEDB;
        *(u32x4*)(h_lds + soff0) = v0;
        *(u32x4*)(h_lds + soff1) = v1;
      }
      __syncthreads();

      // ---- z (own 16 cols) + r (all 512 cols: wave wid -> cols wid*64..+63) ----
      f32x4 ze = {}, racc[4] = {};
      #pragma unroll
      for (int kk = 0; kk < 16; ++kk) {
        bf16x8 a = *(const bf16x8*)(h_lds + (fbase ^ (kk * 64)));
        ze = __builtin_amdgcn_mfma_f32_16x16x32_bf16(a, __builtin_bit_cast(bf16x8, Bz[kk]), ze, 0, 0, 0);
        #pragma unroll
        for (int nf = 0; nf < 4; ++nf) {
          u32x4 bw = *(const u32x4*)(Wrh + (long)(wid * 64 + nf * 16 + l15) * 512 + kk * 32 + kb);
          racc[nf] = __builtin_amdgcn_mfma_f32_16x16x32_bf16(a, __builtin_bit_cast(bf16x8, bw), racc[nf], 0, 0, 0);
        }
      }
      // r*h -> rh_lds (wg-local; h read back from LDS)
      #pragma unroll
      for (int nf = 0; nf < 4; ++nf) {
        int col = wid * 64 + nf * 16 + l15;
        #pragma unroll
        for (int rr = 0; rr < 4; ++rr) {
          int row = q * 4 + rr;
          float xrv = X[(long)((b0 + row) * 64 + t) * 1536 + 512 + col];
          float rv = sigmoidf_(racc[nf][rr] + xrv);
          int byteoff = (row * 1024 + col * 2) ^ ((row & 7) << 4);
          float hv = (float)*(const bf16*)(h_lds + byteoff);
          *(bf16*)(rh_lds + byteoff) = (bf16)(rv * hv);
        }
      }
      f32x4 zf;
      #pragma unroll
      for (int r = 0; r < 4; ++r) {
        float xzv = X[(long)((b0 + q * 4 + r) * 64 + t) * 1536 + ocol];
        zf[r] = sigmoidf_(ze[r] + xzv);
      }
      __syncthreads();          // rh tile complete (intra-wg only)

      // ---- h_tilde (own cols) + blend; h -> hs slab t+1 ----
      f32x4 he = {};
      #pragma unroll
      for (int kk = 0; kk < 16; ++kk) {
        bf16x8 a = *(const bf16x8*)(rh_lds + (fbase ^ (kk * 64)));
        he = __builtin_amdgcn_mfma_f32_16x16x32_bf16(a, __builtin_bit_cast(bf16x8, Bh[kk]), he, 0, 0, 0);
      }
      bf16* ph = hs + (long)((t + 1) * 32 + b0 + q * 4) * 512 + ocol;
      #pragma unroll
      for (int r = 0; r < 4; ++r) {
        float xhv = X[(long)((b0 + q * 4 + r) * 64 + t) * 1536 + 1024 + ocol];
        float ht = tanhf(he[r] + xhv);
        float hn = hprev[r] + zf[r] * (ht - hprev[r]);   // (1-z)h + z*ht
        hprev[r] = hn;
      }
      GST2(ph, "0", hprev[0]); GST2(ph, "1024", hprev[1]);
      GST2(ph, "2048", hprev[2]); GST2(ph, "3072", hprev[3]);
      ++epoch;
      WAITV;                    // h(t+1) stores at LLC
      __syncthreads();          // all waves drained + done with LDS tiles
      if (tid == 0) {
        __hip_atomic_fetch_add(mctr, 1, __ATOMIC_RELAXED, __HIP_MEMORY_SCOPE_AGENT);
        while (__hip_atomic_load(mctr, __ATOMIC_RELAXED, __HIP_MEMORY_SCOPE_AGENT) < 4 * epoch)
          __builtin_amdgcn_s_sleep(1);
        if ((bid & 3) == 0 && (t & 3) == 3) {   // group leader publishes prog
          int e = epoch;
          asm volatile("global_store_dword %0, %1, off sc0 sc1" :: "v"(progG), "v"(e) : "memory");
        }
      }
      __syncthreads();
    }
    return;
  }

  // ================= logits worker: 128x128 tile, 8 waves, dual-flag gated =============
  const int lwg   = bid - NWG_REC;
  const int mtile = lwg / NTILES;       // mtile-slow
  const int ntile = lwg % NTILES;
  const int m0 = mtile * 128, n0 = ntile * 128;

  if (tid < 2) {                        // lane 0: group 0, lane 1: group 1
    const int tgt = 4 * (mtile + 1);    // epoch after step 4*mtile+3
    const int* p = ctr + 64 + tid * 32;
    while (llc_poll(p) < tgt) __builtin_amdgcn_s_sleep(32);
  }
  __syncthreads();

  const bf16* hsW = hs + 16384;         // skip slab 0 (h0): row rr = t*32+b
  bf16* lA = (bf16*)smem;               // [128][40]
  bf16* lB = (bf16*)(smem + 10240);     // [128][40]
  const int kb8  = q * 8;
  const int wid  = tid >> 6;            // 0..7
  const int wm   = wid >> 1;            // 0..3 -> 32 rows each
  const int wn   = wid & 1;             // 0..1 -> 64 cols each
  const int arow = tid >> 2;
  const int akc  = (tid & 3) * 8;

  f32x4 acc[2][4] = {};

  for (int k0 = 0; k0 < 512; k0 += 32) {
    u32x4 av = *(const u32x4*)(hsW + (long)(m0 + arow) * 512 + k0 + akc);  // cached
    bf16x8 bv;
    if (use_bf16B) bv = *(const bf16x8*)(fcw16 + (long)(n0 + arow) * 512 + k0 + akc);
    else           bv = cvt8(fcw_f32 + (long)(n0 + arow) * 512 + k0 + akc);
    *(u32x4*)&lA[arow * 40 + akc] = av;
    *(bf16x8*)&lB[arow * 40 + akc] = bv;
    __syncthreads();
    bf16x8 af[2], bfr[4];
    #pragma unroll
    for (int mf = 0; mf < 2; ++mf)
      af[mf] = *(const bf16x8*)&lA[(wm * 32 + mf * 16 + l15) * 40 + kb8];
    #pragma unroll
    for (int nf = 0; nf < 4; ++nf)
      bfr[nf] = *(const bf16x8*)&lB[(wn * 64 + nf * 16 + l15) * 40 + kb8];
    #pragma unroll
    for (int mf = 0; mf < 2; ++mf)
      #pragma unroll
      for (int nf = 0; nf < 4; ++nf)
        acc[mf][nf] = __builtin_amdgcn_mfma_f32_16x16x32_bf16(af[mf], bfr[nf], acc[mf][nf], 0, 0, 0);
    __syncthreads();
  }

  // epilogue: remap t-major row rr = t*32+b -> out row b*64+t
  #pragma unroll
  for (int mf = 0; mf < 2; ++mf)
    #pragma unroll
    for (int nf = 0; nf < 4; ++nf) {
      int col = n0 + wn * 64 + nf * 16 + l15;
      float bias_v = fc_b[col];
      #pragma unroll
      for (int r = 0; r < 4; ++r) {
        int rr = m0 + wm * 32 + mf * 16 + q * 4 + r;
        int tt = rr >> 5, b = rr & 31;
        out[(long)(b * 64 + tt) * 32000 + col] = acc[mf][nf][r] + bias_v;
      }
    }
}

// ---------------- host ----------------
extern "C" void kernel_launch(void* const* d_in, const int* in_sizes, int n_in,
                              void* d_out, int out_size, void* d_ws, size_t ws_size,
                              hipStream_t stream) {
  const float* feat = (const float*)d_in[0];
  const int*   caps = (const int*)d_in[1];
  const float* emb  = (const float*)d_in[2];
  const float* Wz_w = (const float*)d_in[3];
  const float* Wz_b = (const float*)d_in[4];
  const float* Wr_w = (const float*)d_in[5];
  const float* Wr_b = (const float*)d_in[6];
  const float* Wh_w = (const float*)d_in[7];
  const float* Wh_b = (const float*)d_in[8];
  const float* fc_w = (const float*)d_in[9];
  const float* fc_b = (const float*)d_in[10];
  float* out = (float*)d_out;

  char* ws = (char*)d_ws;
  float* X_all = (float*)(ws + 0);              // 12,582,912
  bf16*  hs    = (bf16*) (ws + 12582912);       // 65*32*512*2 = 2,129,920 (slab 0 = h0)
  bf16*  Whp   = (bf16*) (ws + 14745600);       // 1,572,864
  int*   ctr   = (int*)  (ws + 16318464);       // 512 B flag area
  bf16*  fcw16 = (bf16*) (ws + 16318976);       // 32,768,000 -> end 49,086,976
  const bool cvt_fc = (ws_size >= (size_t)49087000);

  // merged prologue: 192 gemm + (cvt_fc ? 128 cvt : 0) + 384 prep blocks
  const int prep_start = cvt_fc ? 320 : 192;
  xproj_k<<<dim3(prep_start + 384), dim3(256), 0, stream>>>(
      caps, emb, Wz_w, Wr_w, Wh_w, Wz_b, Wr_b, Wh_b, X_all, 192, prep_start,
      fc_w, fcw16, feat, hs, ctr, Whp);

  // fused: 8 recurrence wgs (1 barrier/step) + 4000 gated logits wgs
  fused_k<<<dim3(NWG_REC + MTILES * NTILES), dim3(512), 0, stream>>>(
      X_all, Whp, Whp + 262144, Whp + 524288, feat, hs, ctr,
      fcw16, fc_w, fc_b, out, cvt_fc ? 1 : 0);
}